// Round 4
// baseline (433.806 us; speedup 1.0000x reference)
//
#include <hip/hip_runtime.h>

#define FDIM 128
#define NRBF 20
constexpr float CUTOFF_F = 5.0f;
constexpr float PI_F = 3.14159265358979323846f;

typedef _Float16 h2 __attribute__((ext_vector_type(2)));

__device__ __forceinline__ uint packh(float a, float b) {
  union { _Float16 h[2]; uint u; } x;
  x.h[0] = (_Float16)a;
  x.h[1] = (_Float16)b;
  return x.u;
}
__device__ __forceinline__ float h_lo(uint w) {
  union { uint u; _Float16 h[2]; } x;
  x.u = w;
  return (float)x.h[0];
}
__device__ __forceinline__ float h_hi(uint w) {
  union { uint u; _Float16 h[2]; } x;
  x.u = w;
  return (float)x.h[1];
}
__device__ __forceinline__ float us2f(ushort u) {
  union { ushort s; _Float16 h; } x;
  x.s = u;
  return (float)x.h;
}
__device__ __forceinline__ ushort f2us(float f) {
  union { _Float16 h; ushort s; } x;
  x.h = (_Float16)f;
  return x.s;
}
__device__ __forceinline__ float dot2(uint cw, h2 w, float acc) {
#if __has_builtin(__builtin_amdgcn_fdot2)
  h2 c = __builtin_bit_cast(h2, cw);
  return __builtin_amdgcn_fdot2(c, w, acc, false);
#else
  return fmaf(h_hi(cw), (float)w[1], fmaf(h_lo(cw), (float)w[0], acc));
#endif
}

// ---------------------------------------------------------------------------
// GEMM: C = act(A[Mx128] @ W[128xN] + bias); OUTH=1 stores _Float16.
// ---------------------------------------------------------------------------
template <int SILU, int OUTH>
__global__ __launch_bounds__(256) void gemm_k128(
    const float* __restrict__ A, const float* __restrict__ W,
    const float* __restrict__ bias, float* __restrict__ Cf,
    ushort* __restrict__ Ch, int M, int Ncols) {
  __shared__ float As[64][FDIM + 4];
  const int row0 = blockIdx.x * 64;
  const int col0 = blockIdx.y * 128;
  const int t = threadIdx.x;

  for (int i = t; i < 64 * 32; i += 256) {
    int r = i >> 5;
    int cc = (i & 31) << 2;
    int gr = row0 + r;
    float4 v = make_float4(0.f, 0.f, 0.f, 0.f);
    if (gr < M) v = *(const float4*)&A[(size_t)gr * FDIM + cc];
    *(float4*)&As[r][cc] = v;
  }
  __syncthreads();

  const int tx = t & 15;
  const int ty = t >> 4;
  const int c0 = col0 + tx * 8;
  const int r0 = ty * 4;

  float acc[4][8];
#pragma unroll
  for (int r = 0; r < 4; ++r)
#pragma unroll
    for (int c = 0; c < 8; ++c) acc[r][c] = 0.f;

#pragma unroll 4
  for (int k = 0; k < FDIM; ++k) {
    const float* wr = W + (size_t)k * Ncols + c0;
    float4 wa = *(const float4*)wr;
    float4 wb = *(const float4*)(wr + 4);
    float w[8] = {wa.x, wa.y, wa.z, wa.w, wb.x, wb.y, wb.z, wb.w};
    float a[4];
#pragma unroll
    for (int r = 0; r < 4; ++r) a[r] = As[r0 + r][k];
#pragma unroll
    for (int r = 0; r < 4; ++r)
#pragma unroll
      for (int c = 0; c < 8; ++c) acc[r][c] = fmaf(a[r], w[c], acc[r][c]);
  }

#pragma unroll
  for (int r = 0; r < 4; ++r) {
    int gr = row0 + r0 + r;
    if (gr >= M) continue;
    float v[8];
#pragma unroll
    for (int c = 0; c < 8; ++c) {
      float x = acc[r][c] + bias[c0 + c];
      if (SILU) x = x / (1.f + __expf(-x));
      v[c] = x;
    }
    if (OUTH) {
      union { ushort s[8]; uint4 q; } p;
#pragma unroll
      for (int c = 0; c < 8; ++c) p.s[c] = f2us(v[c]);
      *(uint4*)&Ch[(size_t)gr * Ncols + c0] = p.q;
    } else {
      float* crow = Cf + (size_t)gr * Ncols + c0;
      *(float4*)crow = make_float4(v[0], v[1], v[2], v[3]);
      *(float4*)(crow + 4) = make_float4(v[4], v[5], v[6], v[7]);
    }
  }
}

// ---------------------------------------------------------------------------
// node_vector f32 [N][128][3]  ->  f16 planes [3][N*128]
// ---------------------------------------------------------------------------
__global__ __launch_bounds__(256) void conv_nvec(const float* __restrict__ nvec,
                                                 ushort* __restrict__ nvh,
                                                 int NF) {
  for (int i = blockIdx.x * blockDim.x + threadIdx.x; i < NF;
       i += gridDim.x * blockDim.x) {
    float x = nvec[(size_t)3 * i];
    float y = nvec[(size_t)3 * i + 1];
    float z = nvec[(size_t)3 * i + 2];
    nvh[i] = f2us(x);
    nvh[(size_t)NF + i] = f2us(y);
    nvh[(size_t)2 * NF + i] = f2us(z);
  }
}

// ---------------------------------------------------------------------------
// CSR build
// ---------------------------------------------------------------------------
__global__ __launch_bounds__(256) void hist_kernel(const float* __restrict__ adj,
                                                   int* __restrict__ counts,
                                                   int E) {
  int e = blockIdx.x * blockDim.x + threadIdx.x;
  if (e < E) atomicAdd(&counts[(int)adj[(size_t)e * 6]], 1);
}

__global__ __launch_bounds__(1024) void scan_kernel(
    const int* __restrict__ counts, int* __restrict__ offs,
    int* __restrict__ cursor, int n) {
  __shared__ int part[1024];
  const int tid = threadIdx.x;
  const int CH = (n + 1023) >> 10;
  const int b = tid * CH;
  const int e = min(b + CH, n);
  int s = 0;
  for (int i = b; i < e; ++i) s += counts[i];
  part[tid] = s;
  __syncthreads();
  for (int off = 1; off < 1024; off <<= 1) {
    int v = (tid >= off) ? part[tid - off] : 0;
    __syncthreads();
    part[tid] += v;
    __syncthreads();
  }
  int run = part[tid] - s;
  if (tid == 0) offs[0] = 0;
  for (int i = b; i < e; ++i) {
    int c = counts[i];
    cursor[i] = run;
    run += c;
    offs[i + 1] = run;
  }
}

// ---------------------------------------------------------------------------
// Edge prep: scatter eid + 64B record:
// w0=src, w1=(rhx,rhy), w2=(rhz,cut), w3..12=(c0,c1)..(c18,c19), c_n=sin(nx)*invd*cut
// ---------------------------------------------------------------------------
__global__ __launch_bounds__(256) void edge_prep(const float* __restrict__ adj,
                                                 int* __restrict__ cursor,
                                                 int* __restrict__ eids,
                                                 uint* __restrict__ rec, int E) {
  int e = blockIdx.x * blockDim.x + threadIdx.x;
  if (e >= E) return;
  const float* a = adj + (size_t)e * 6;
  int dst = (int)a[0];
  int src = (int)a[1];
  float rx = a[2], ry = a[3], rz = a[4], d = a[5];

  int p = atomicAdd(&cursor[dst], 1);
  eids[p] = e;

  float x = d * (PI_F / CUTOFF_F);
  float sx, cx;
  __sincosf(x, &sx, &cx);
  float invd = 1.f / d;
  float cut = (d < CUTOFF_F) ? 0.5f * (cx + 1.f) : 0.f;
  float sc = invd * cut;

  union { uint w[16]; uint4 q[4]; } R;
  R.w[0] = (uint)src;
  R.w[1] = packh(rx * invd, ry * invd);
  R.w[2] = packh(rz * invd, cut);
  float twoc = 2.f * cx;
  float sprev = 0.f, scur = sx;
  float c[NRBF];
#pragma unroll
  for (int n = 0; n < NRBF; ++n) {
    c[n] = scur * sc;
    float nxt = fmaf(twoc, scur, -sprev);
    sprev = scur;
    scur = nxt;
  }
#pragma unroll
  for (int m = 0; m < 10; ++m) R.w[3 + m] = packh(c[2 * m], c[2 * m + 1]);
  R.w[13] = 0;
  R.w[14] = 0;
  R.w[15] = 0;
  uint4* o = (uint4*)(rec + ((size_t)e << 4));
#pragma unroll
  for (int m = 0; m < 4; ++m) o[m] = R.q[m];
}

// ---------------------------------------------------------------------------
// Per-dst accumulation: 256 threads = 2 dst nodes per block.
// NVH=1: gather node_vector from f16 planes; NVH=0: from f32.
// ---------------------------------------------------------------------------
template <int NVH>
__global__ __launch_bounds__(256) void accum_kernel(
    const uint* __restrict__ rec, const ushort* __restrict__ atomh,
    const ushort* __restrict__ nvh, const float* __restrict__ nvec,
    const float* __restrict__ Wr, const float* __restrict__ br,
    const float* __restrict__ ns, const int* __restrict__ offs,
    const int* __restrict__ eids, float* __restrict__ out_s,
    float* __restrict__ out_v, int Nn) {
  const int half = threadIdx.x >> 7;
  const int j = threadIdx.x & 127;
  const int d = blockIdx.x * 2 + half;
  const bool active = d < Nn;
  const size_t NF = (size_t)Nn * FDIM;

  h2 wp0[10], wp1[10], wp2[10];
#pragma unroll
  for (int m = 0; m < 10; ++m) {
    wp0[m] = h2{(_Float16)Wr[(2 * m) * 384 + j], (_Float16)Wr[(2 * m + 1) * 384 + j]};
    wp1[m] = h2{(_Float16)Wr[(2 * m) * 384 + 128 + j], (_Float16)Wr[(2 * m + 1) * 384 + 128 + j]};
    wp2[m] = h2{(_Float16)Wr[(2 * m) * 384 + 256 + j], (_Float16)Wr[(2 * m + 1) * 384 + 256 + j]};
  }
  const float brj0 = br[j], brj1 = br[j + 128], brj2 = br[j + 256];

  __shared__ int sh_e[2][128], sh_s[2][128];
  int beg = 0, cnt = 0;
  if (active) {
    beg = offs[d];
    cnt = offs[d + 1] - beg;
  }
  const int m = cnt < 128 ? cnt : 128;
  if (j < m) sh_e[half][j] = eids[beg + j];
  __syncthreads();
  if (j < m) {  // parallel rank sort (eids unique)
    int v = sh_e[half][j];
    int r = 0;
    for (int u = 0; u < m; ++u) r += (sh_e[half][u] < v);
    sh_s[half][r] = v;
  }
  __syncthreads();
  if (!active) return;

#define EID(t) ((t) < 128 ? sh_s[half][(t)] : eids[beg + (t)])
#define LOADREC(R, t)                                                      \
  {                                                                        \
    int eu = __builtin_amdgcn_readfirstlane(EID(t));                       \
    const uint* p = rec + ((size_t)(uint)eu << 4);                         \
    _Pragma("unroll") for (int w_ = 0; w_ < 13; ++w_) R[w_] = p[w_];       \
  }
#define LOADVAL(A0, A1, A2, V0, V1, V2, SRC)                               \
  {                                                                        \
    const ushort* ab = atomh + (size_t)(SRC)*384;                          \
    A0 = us2f(ab[j]);                                                      \
    A1 = us2f(ab[j + 128]);                                                \
    A2 = us2f(ab[j + 256]);                                                \
    if (NVH) {                                                             \
      const ushort* vb = nvh + (size_t)(SRC)*FDIM + j;                     \
      V0 = us2f(vb[0]);                                                    \
      V1 = us2f(vb[NF]);                                                   \
      V2 = us2f(vb[2 * NF]);                                               \
    } else {                                                               \
      const float* vb = nvec + (size_t)(SRC)*384 + j * 3;                  \
      V0 = vb[0];                                                          \
      V1 = vb[1];                                                          \
      V2 = vb[2];                                                          \
    }                                                                      \
  }

  float acc_s = 0.f, av0 = 0.f, av1 = 0.f, av2 = 0.f;

  uint r_cur[13], r_nxt[13];
  float pa0 = 0, pa1 = 0, pa2 = 0, pv0 = 0, pv1 = 0, pv2 = 0;
  if (cnt > 0) LOADREC(r_cur, 0);
  if (cnt > 1) LOADREC(r_nxt, 1);
  if (cnt > 0) LOADVAL(pa0, pa1, pa2, pv0, pv1, pv2, (int)r_cur[0]);

  for (int t = 0; t < cnt; ++t) {
    float na0 = 0, na1 = 0, na2 = 0, nv0 = 0, nv1 = 0, nv2 = 0;
    if (t + 1 < cnt) LOADVAL(na0, na1, na2, nv0, nv1, nv2, (int)r_nxt[0]);
    uint r_n2[13];
    if (t + 2 < cnt) LOADREC(r_n2, t + 2);

    float rhx = h_lo(r_cur[1]), rhy = h_hi(r_cur[1]);
    float rhz = h_lo(r_cur[2]), cut = h_hi(r_cur[2]);
    float w0 = cut * brj0, w1 = cut * brj1, w2 = cut * brj2;
#pragma unroll
    for (int q = 0; q < 10; ++q) {
      w0 = dot2(r_cur[3 + q], wp0[q], w0);
      w1 = dot2(r_cur[3 + q], wp1[q], w1);
      w2 = dot2(r_cur[3 + q], wp2[q], w2);
    }
    float s1 = pa0 * w0;
    float s2 = pa1 * w1;
    float s3 = pa2 * w2;
    acc_s += s2;
    av0 = fmaf(pv0, s1, fmaf(s3, rhx, av0));
    av1 = fmaf(pv1, s1, fmaf(s3, rhy, av1));
    av2 = fmaf(pv2, s1, fmaf(s3, rhz, av2));

#pragma unroll
    for (int w_ = 0; w_ < 13; ++w_) {
      r_cur[w_] = r_nxt[w_];
      r_nxt[w_] = r_n2[w_];
    }
    pa0 = na0; pa1 = na1; pa2 = na2;
    pv0 = nv0; pv1 = nv1; pv2 = nv2;
  }

  out_s[(size_t)d * FDIM + j] = ns[(size_t)d * FDIM + j] + acc_s;
  float* vo = out_v + (size_t)d * 384 + j * 3;
  const float* vi = nvec + (size_t)d * 384 + j * 3;
  vo[0] = vi[0] + av0;
  vo[1] = vi[1] + av1;
  vo[2] = vi[2] + av2;
#undef EID
#undef LOADREC
#undef LOADVAL
}

// ---------------------------------------------------------------------------
extern "C" void kernel_launch(void* const* d_in, const int* in_sizes, int n_in,
                              void* d_out, int out_size, void* d_ws,
                              size_t ws_size, hipStream_t stream) {
  const float* node_scalar = (const float*)d_in[0];
  const float* node_vector = (const float*)d_in[1];
  const float* adj = (const float*)d_in[2];
  const float* W1 = (const float*)d_in[3];
  const float* b1 = (const float*)d_in[4];
  const float* W2 = (const float*)d_in[5];
  const float* b2 = (const float*)d_in[6];
  const float* Wr = (const float*)d_in[7];
  const float* br = (const float*)d_in[8];

  const int N = in_sizes[0] / FDIM;
  const int E = in_sizes[2] / 6;

  float* out = (float*)d_out;
  float* out_s = out;
  float* out_v = out + (size_t)N * FDIM;

  // workspace: atomh | rec | [nvech] | counts | offs | cursor | eids
  char* w = (char*)d_ws;
  ushort* atomh = (ushort*)w;
  size_t off = (size_t)N * 384 * 2;
  uint* rec = (uint*)(w + off);
  off += (size_t)E * 64;
  const size_t nvh_bytes = (size_t)3 * N * FDIM * 2;
  const size_t int_bytes = ((size_t)3 * N + 1 + E) * 4;
  const bool use_nvh = (off + nvh_bytes + int_bytes) <= ws_size;
  ushort* nvh = nullptr;
  if (use_nvh) {
    nvh = (ushort*)(w + off);
    off += nvh_bytes;
  }
  int* counts = (int*)(w + off);
  int* offs = counts + N;
  int* cursor = offs + N + 1;
  int* eids = cursor + N;

  float* h = out_s;  // N x 128, dead until accum's final write

  hipMemsetAsync(counts, 0, (size_t)N * sizeof(int), stream);
  hist_kernel<<<(E + 255) / 256, 256, 0, stream>>>(adj, counts, E);
  scan_kernel<<<1, 1024, 0, stream>>>(counts, offs, cursor, N);
  edge_prep<<<(E + 255) / 256, 256, 0, stream>>>(adj, cursor, eids, rec, E);
  if (use_nvh)
    conv_nvec<<<2048, 256, 0, stream>>>(node_vector, nvh, N * FDIM);

  dim3 g1((N + 63) / 64, 1);
  gemm_k128<1, 0><<<g1, 256, 0, stream>>>(node_scalar, W1, b1, h, nullptr, N, 128);
  dim3 g2((N + 63) / 64, 3);
  gemm_k128<0, 1><<<g2, 256, 0, stream>>>(h, W2, b2, nullptr, atomh, N, 384);

  if (use_nvh)
    accum_kernel<1><<<(N + 1) / 2, 256, 0, stream>>>(
        rec, atomh, nvh, node_vector, Wr, br, node_scalar, offs, eids, out_s,
        out_v, N);
  else
    accum_kernel<0><<<(N + 1) / 2, 256, 0, stream>>>(
        rec, atomh, nullptr, node_vector, Wr, br, node_scalar, offs, eids,
        out_s, out_v, N);
}

// Round 5
// 356.322 us; speedup vs baseline: 1.2175x; 1.2175x over previous
//
#include <hip/hip_runtime.h>

#define FDIM 128
#define NRBF 20
constexpr float CUTOFF_F = 5.0f;
constexpr float PI_F = 3.14159265358979323846f;

typedef _Float16 h2 __attribute__((ext_vector_type(2)));

__device__ __forceinline__ uint packh(float a, float b) {
  union { _Float16 h[2]; uint u; } x;
  x.h[0] = (_Float16)a;
  x.h[1] = (_Float16)b;
  return x.u;
}
__device__ __forceinline__ float h_lo(uint w) {
  union { uint u; _Float16 h[2]; } x;
  x.u = w;
  return (float)x.h[0];
}
__device__ __forceinline__ float h_hi(uint w) {
  union { uint u; _Float16 h[2]; } x;
  x.u = w;
  return (float)x.h[1];
}
__device__ __forceinline__ float us2f(ushort u) {
  union { ushort s; _Float16 h; } x;
  x.s = u;
  return (float)x.h;
}
__device__ __forceinline__ ushort f2us(float f) {
  union { _Float16 h; ushort s; } x;
  x.h = (_Float16)f;
  return x.s;
}
__device__ __forceinline__ float dot2(uint cw, h2 w, float acc) {
#if __has_builtin(__builtin_amdgcn_fdot2)
  h2 c = __builtin_bit_cast(h2, cw);
  return __builtin_amdgcn_fdot2(c, w, acc, false);
#else
  return fmaf(h_hi(cw), (float)w[1], fmaf(h_lo(cw), (float)w[0], acc));
#endif
}

// ---------------------------------------------------------------------------
// Fused GEMM: atomh[M x 384](f16) = silu(ns @ W1 + b1) @ W2 + b2
// h tile lives only in LDS (As buffer reused after phase 1).
// 64-row tile / block, 256 threads, 4x8 outputs per thread per col-panel.
// ---------------------------------------------------------------------------
__global__ __launch_bounds__(256) void gemm_fused(
    const float* __restrict__ A, const float* __restrict__ W1,
    const float* __restrict__ b1, const float* __restrict__ W2,
    const float* __restrict__ b2, ushort* __restrict__ atomh, int M) {
  __shared__ float As[64][FDIM + 4];
  const int row0 = blockIdx.x * 64;
  const int t = threadIdx.x;
  const int tx = t & 15;
  const int ty = t >> 4;
  const int cl = tx * 8;  // local col 0..127
  const int r0 = ty * 4;

  // stage ns tile
  for (int i = t; i < 64 * 32; i += 256) {
    int r = i >> 5;
    int cc = (i & 31) << 2;
    int gr = row0 + r;
    float4 v = make_float4(0.f, 0.f, 0.f, 0.f);
    if (gr < M) v = *(const float4*)&A[(size_t)gr * FDIM + cc];
    *(float4*)&As[r][cc] = v;
  }
  __syncthreads();

  // phase 1: h = silu(As @ W1 + b1), 128 cols
  float acc[4][8];
#pragma unroll
  for (int r = 0; r < 4; ++r)
#pragma unroll
    for (int c = 0; c < 8; ++c) acc[r][c] = 0.f;
#pragma unroll 4
  for (int k = 0; k < FDIM; ++k) {
    const float* wr = W1 + (size_t)k * FDIM + cl;
    float4 wa = *(const float4*)wr;
    float4 wb = *(const float4*)(wr + 4);
    float w[8] = {wa.x, wa.y, wa.z, wa.w, wb.x, wb.y, wb.z, wb.w};
    float a[4];
#pragma unroll
    for (int r = 0; r < 4; ++r) a[r] = As[r0 + r][k];
#pragma unroll
    for (int r = 0; r < 4; ++r)
#pragma unroll
      for (int c = 0; c < 8; ++c) acc[r][c] = fmaf(a[r], w[c], acc[r][c]);
  }
  float hv[4][8];
#pragma unroll
  for (int r = 0; r < 4; ++r)
#pragma unroll
    for (int c = 0; c < 8; ++c) {
      float x = acc[r][c] + b1[cl + c];
      hv[r][c] = x / (1.f + __expf(-x));
    }
  __syncthreads();  // all As reads done
#pragma unroll
  for (int r = 0; r < 4; ++r)
#pragma unroll
    for (int c = 0; c < 8; ++c) As[r0 + r][cl + c] = hv[r][c];
  __syncthreads();  // h tile ready in As

  // phase 2: atom = h @ W2 + b2, 3 panels of 128 cols
#pragma unroll 1
  for (int p = 0; p < 3; ++p) {
    const int c0 = p * 128 + cl;
#pragma unroll
    for (int r = 0; r < 4; ++r)
#pragma unroll
      for (int c = 0; c < 8; ++c) acc[r][c] = 0.f;
#pragma unroll 4
    for (int k = 0; k < FDIM; ++k) {
      const float* wr = W2 + (size_t)k * 384 + c0;
      float4 wa = *(const float4*)wr;
      float4 wb = *(const float4*)(wr + 4);
      float w[8] = {wa.x, wa.y, wa.z, wa.w, wb.x, wb.y, wb.z, wb.w};
      float a[4];
#pragma unroll
      for (int r = 0; r < 4; ++r) a[r] = As[r0 + r][k];
#pragma unroll
      for (int r = 0; r < 4; ++r)
#pragma unroll
        for (int c = 0; c < 8; ++c) acc[r][c] = fmaf(a[r], w[c], acc[r][c]);
    }
#pragma unroll
    for (int r = 0; r < 4; ++r) {
      int gr = row0 + r0 + r;
      if (gr >= M) continue;
      union { ushort s[8]; uint4 q; } pk;
#pragma unroll
      for (int c = 0; c < 8; ++c) pk.s[c] = f2us(acc[r][c] + b2[c0 + c]);
      *(uint4*)&atomh[(size_t)gr * 384 + c0] = pk.q;
    }
  }
}

// ---------------------------------------------------------------------------
// node_vector f32 [N][128][3] -> f16 planes [3][N*128]
// ---------------------------------------------------------------------------
__global__ __launch_bounds__(256) void conv_nvec(const float* __restrict__ nvec,
                                                 ushort* __restrict__ nvh,
                                                 int NF) {
  for (int i = blockIdx.x * blockDim.x + threadIdx.x; i < NF;
       i += gridDim.x * blockDim.x) {
    nvh[i] = f2us(nvec[(size_t)3 * i]);
    nvh[(size_t)NF + i] = f2us(nvec[(size_t)3 * i + 1]);
    nvh[(size_t)2 * NF + i] = f2us(nvec[(size_t)3 * i + 2]);
  }
}

// ---------------------------------------------------------------------------
// CSR build
// ---------------------------------------------------------------------------
__global__ __launch_bounds__(256) void hist_kernel(const float* __restrict__ adj,
                                                   int* __restrict__ counts,
                                                   int E) {
  int e = blockIdx.x * blockDim.x + threadIdx.x;
  if (e < E) atomicAdd(&counts[(int)adj[(size_t)e * 6]], 1);
}

__global__ __launch_bounds__(1024) void scan_kernel(
    const int* __restrict__ counts, int* __restrict__ offs,
    int* __restrict__ cursor, int n) {
  __shared__ int part[1024];
  const int tid = threadIdx.x;
  const int CH = (n + 1023) >> 10;
  const int b = tid * CH;
  const int e = min(b + CH, n);
  int s = 0;
  for (int i = b; i < e; ++i) s += counts[i];
  part[tid] = s;
  __syncthreads();
  for (int off = 1; off < 1024; off <<= 1) {
    int v = (tid >= off) ? part[tid - off] : 0;
    __syncthreads();
    part[tid] += v;
    __syncthreads();
  }
  int run = part[tid] - s;
  if (tid == 0) offs[0] = 0;
  for (int i = b; i < e; ++i) {
    int c = counts[i];
    cursor[i] = run;
    run += c;
    offs[i + 1] = run;
  }
}

// ---------------------------------------------------------------------------
// Edge prep: scatter eid + 64B record:
// w0=src, w1=(rhx,rhy), w2=(rhz,cut), w3..12=(c0..c19), c_n=sin(nx)*invd*cut
// ---------------------------------------------------------------------------
__global__ __launch_bounds__(256) void edge_prep(const float* __restrict__ adj,
                                                 int* __restrict__ cursor,
                                                 int* __restrict__ eids,
                                                 uint* __restrict__ rec, int E) {
  int e = blockIdx.x * blockDim.x + threadIdx.x;
  if (e >= E) return;
  const float* a = adj + (size_t)e * 6;
  int dst = (int)a[0];
  int src = (int)a[1];
  float rx = a[2], ry = a[3], rz = a[4], d = a[5];

  int p = atomicAdd(&cursor[dst], 1);
  eids[p] = e;

  float x = d * (PI_F / CUTOFF_F);
  float sx, cx;
  __sincosf(x, &sx, &cx);
  float invd = 1.f / d;
  float cut = (d < CUTOFF_F) ? 0.5f * (cx + 1.f) : 0.f;
  float sc = invd * cut;

  union { uint w[16]; uint4 q[4]; } R;
  R.w[0] = (uint)src;
  R.w[1] = packh(rx * invd, ry * invd);
  R.w[2] = packh(rz * invd, cut);
  float twoc = 2.f * cx;
  float sprev = 0.f, scur = sx;
  float c[NRBF];
#pragma unroll
  for (int n = 0; n < NRBF; ++n) {
    c[n] = scur * sc;
    float nxt = fmaf(twoc, scur, -sprev);
    sprev = scur;
    scur = nxt;
  }
#pragma unroll
  for (int m = 0; m < 10; ++m) R.w[3 + m] = packh(c[2 * m], c[2 * m + 1]);
  R.w[13] = 0;
  R.w[14] = 0;
  R.w[15] = 0;
  uint4* o = (uint4*)(rec + ((size_t)e << 4));
#pragma unroll
  for (int m = 0; m < 4; ++m) o[m] = R.q[m];
}

// ---------------------------------------------------------------------------
// Persistent per-dst accumulation: 128 threads, grid-stride over dst nodes.
// Wr/br hoisted once per block. NVH=1: f16-plane nvec gathers.
// ---------------------------------------------------------------------------
template <int NVH>
__global__ __launch_bounds__(128) void accum_kernel(
    const uint* __restrict__ rec, const ushort* __restrict__ atomh,
    const ushort* __restrict__ nvh, const float* __restrict__ nvec,
    const float* __restrict__ Wr, const float* __restrict__ br,
    const float* __restrict__ ns, const int* __restrict__ offs,
    const int* __restrict__ eids, float* __restrict__ out_s,
    float* __restrict__ out_v, int Nn) {
  const int j = threadIdx.x;
  const int NF = Nn * FDIM;

  h2 wp0[10], wp1[10], wp2[10];
#pragma unroll
  for (int m = 0; m < 10; ++m) {
    wp0[m] = h2{(_Float16)Wr[(2 * m) * 384 + j], (_Float16)Wr[(2 * m + 1) * 384 + j]};
    wp1[m] = h2{(_Float16)Wr[(2 * m) * 384 + 128 + j], (_Float16)Wr[(2 * m + 1) * 384 + 128 + j]};
    wp2[m] = h2{(_Float16)Wr[(2 * m) * 384 + 256 + j], (_Float16)Wr[(2 * m + 1) * 384 + 256 + j]};
  }
  const float brj0 = br[j], brj1 = br[j + 128], brj2 = br[j + 256];

  __shared__ int sh_e[128], sh_s[128];

#define EID(t) ((t) < 128 ? sh_s[(t)] : eids[beg + (t)])
#define LOADREC(R, t)                                                      \
  {                                                                        \
    int eu = __builtin_amdgcn_readfirstlane(EID(t));                       \
    const uint* p = rec + ((size_t)(uint)eu << 4);                         \
    _Pragma("unroll") for (int w_ = 0; w_ < 13; ++w_) R[w_] = p[w_];       \
  }
#define LOADVAL(A0, A1, A2, V0, V1, V2, SRC)                               \
  {                                                                        \
    const ushort* ab = atomh + (size_t)(SRC)*384;                          \
    A0 = us2f(ab[j]);                                                      \
    A1 = us2f(ab[j + 128]);                                                \
    A2 = us2f(ab[j + 256]);                                                \
    if (NVH) {                                                             \
      const ushort* vb = nvh + ((SRC) << 7) + j;                           \
      V0 = us2f(vb[0]);                                                    \
      V1 = us2f(vb[NF]);                                                   \
      V2 = us2f(vb[2 * NF]);                                               \
    } else {                                                               \
      const float* vb = nvec + (size_t)(SRC)*384 + j * 3;                  \
      V0 = vb[0];                                                          \
      V1 = vb[1];                                                          \
      V2 = vb[2];                                                          \
    }                                                                      \
  }

  for (int d = blockIdx.x; d < Nn; d += gridDim.x) {
    const int beg = offs[d];
    const int cnt = offs[d + 1] - beg;
    const int m = cnt < 128 ? cnt : 128;
    if (j < m) sh_e[j] = eids[beg + j];
    __syncthreads();  // sh_e ready; prior iteration's sh_s reads complete
    if (j < m) {      // parallel rank sort (eids unique)
      int v = sh_e[j];
      int r = 0;
      for (int u = 0; u < m; ++u) r += (sh_e[u] < v);
      sh_s[r] = v;
    }
    __syncthreads();

    float acc_s = 0.f, av0 = 0.f, av1 = 0.f, av2 = 0.f;

    uint r_cur[13], r_nxt[13];
    float pa0 = 0, pa1 = 0, pa2 = 0, pv0 = 0, pv1 = 0, pv2 = 0;
    if (cnt > 0) LOADREC(r_cur, 0);
    if (cnt > 1) LOADREC(r_nxt, 1);
    if (cnt > 0) LOADVAL(pa0, pa1, pa2, pv0, pv1, pv2, (int)r_cur[0]);

    for (int t = 0; t < cnt; ++t) {
      float na0 = 0, na1 = 0, na2 = 0, nv0 = 0, nv1 = 0, nv2 = 0;
      if (t + 1 < cnt) LOADVAL(na0, na1, na2, nv0, nv1, nv2, (int)r_nxt[0]);
      uint r_n2[13];
      if (t + 2 < cnt) LOADREC(r_n2, t + 2);

      float rhx = h_lo(r_cur[1]), rhy = h_hi(r_cur[1]);
      float rhz = h_lo(r_cur[2]), cut = h_hi(r_cur[2]);
      float w0 = cut * brj0, w1 = cut * brj1, w2 = cut * brj2;
#pragma unroll
      for (int q = 0; q < 10; ++q) {
        w0 = dot2(r_cur[3 + q], wp0[q], w0);
        w1 = dot2(r_cur[3 + q], wp1[q], w1);
        w2 = dot2(r_cur[3 + q], wp2[q], w2);
      }
      float s1 = pa0 * w0;
      float s2 = pa1 * w1;
      float s3 = pa2 * w2;
      acc_s += s2;
      av0 = fmaf(pv0, s1, fmaf(s3, rhx, av0));
      av1 = fmaf(pv1, s1, fmaf(s3, rhy, av1));
      av2 = fmaf(pv2, s1, fmaf(s3, rhz, av2));

#pragma unroll
      for (int w_ = 0; w_ < 13; ++w_) {
        r_cur[w_] = r_nxt[w_];
        r_nxt[w_] = r_n2[w_];
      }
      pa0 = na0; pa1 = na1; pa2 = na2;
      pv0 = nv0; pv1 = nv1; pv2 = nv2;
    }

    out_s[(size_t)d * FDIM + j] = ns[(size_t)d * FDIM + j] + acc_s;
    float* vo = out_v + (size_t)d * 384 + j * 3;
    const float* vi = nvec + (size_t)d * 384 + j * 3;
    vo[0] = vi[0] + av0;
    vo[1] = vi[1] + av1;
    vo[2] = vi[2] + av2;
  }
#undef EID
#undef LOADREC
#undef LOADVAL
}

// ---------------------------------------------------------------------------
extern "C" void kernel_launch(void* const* d_in, const int* in_sizes, int n_in,
                              void* d_out, int out_size, void* d_ws,
                              size_t ws_size, hipStream_t stream) {
  const float* node_scalar = (const float*)d_in[0];
  const float* node_vector = (const float*)d_in[1];
  const float* adj = (const float*)d_in[2];
  const float* W1 = (const float*)d_in[3];
  const float* b1 = (const float*)d_in[4];
  const float* W2 = (const float*)d_in[5];
  const float* b2 = (const float*)d_in[6];
  const float* Wr = (const float*)d_in[7];
  const float* br = (const float*)d_in[8];

  const int N = in_sizes[0] / FDIM;
  const int E = in_sizes[2] / 6;

  float* out = (float*)d_out;
  float* out_s = out;
  float* out_v = out + (size_t)N * FDIM;

  // workspace: atomh | rec | [nvh] | counts | offs | cursor | eids
  char* w = (char*)d_ws;
  ushort* atomh = (ushort*)w;
  size_t off = (size_t)N * 384 * 2;
  uint* rec = (uint*)(w + off);
  off += (size_t)E * 64;
  const size_t nvh_bytes = (size_t)3 * N * FDIM * 2;
  const size_t int_bytes = ((size_t)3 * N + 1 + E) * 4;
  const bool use_nvh = (off + nvh_bytes + int_bytes) <= ws_size;
  ushort* nvh = nullptr;
  if (use_nvh) {
    nvh = (ushort*)(w + off);
    off += nvh_bytes;
  }
  int* counts = (int*)(w + off);
  int* offs = counts + N;
  int* cursor = offs + N + 1;
  int* eids = cursor + N;

  hipMemsetAsync(counts, 0, (size_t)N * sizeof(int), stream);
  hist_kernel<<<(E + 255) / 256, 256, 0, stream>>>(adj, counts, E);
  scan_kernel<<<1, 1024, 0, stream>>>(counts, offs, cursor, N);
  edge_prep<<<(E + 255) / 256, 256, 0, stream>>>(adj, cursor, eids, rec, E);
  if (use_nvh)
    conv_nvec<<<2048, 256, 0, stream>>>(node_vector, nvh, N * FDIM);

  gemm_fused<<<(N + 63) / 64, 256, 0, stream>>>(node_scalar, W1, b1, W2, b2,
                                                atomh, N);

  const int agrid = N < 4096 ? N : 4096;
  if (use_nvh)
    accum_kernel<1><<<agrid, 128, 0, stream>>>(rec, atomh, nvh, node_vector,
                                               Wr, br, node_scalar, offs, eids,
                                               out_s, out_v, N);
  else
    accum_kernel<0><<<agrid, 128, 0, stream>>>(rec, atomh, nullptr, node_vector,
                                               Wr, br, node_scalar, offs, eids,
                                               out_s, out_v, N);
}

// Round 6
// 341.379 us; speedup vs baseline: 1.2707x; 1.0438x over previous
//
#include <hip/hip_runtime.h>

#define FDIM 128
#define NRBF 20
constexpr float CUTOFF_F = 5.0f;
constexpr float PI_F = 3.14159265358979323846f;

typedef _Float16 h2 __attribute__((ext_vector_type(2)));

__device__ __forceinline__ uint packh(float a, float b) {
  union { _Float16 h[2]; uint u; } x;
  x.h[0] = (_Float16)a;
  x.h[1] = (_Float16)b;
  return x.u;
}
__device__ __forceinline__ float h_lo(uint w) {
  union { uint u; _Float16 h[2]; } x;
  x.u = w;
  return (float)x.h[0];
}
__device__ __forceinline__ float h_hi(uint w) {
  union { uint u; _Float16 h[2]; } x;
  x.u = w;
  return (float)x.h[1];
}
__device__ __forceinline__ ushort f2us(float f) {
  union { _Float16 h; ushort s; } x;
  x.h = (_Float16)f;
  return x.s;
}
__device__ __forceinline__ float dot2(uint cw, h2 w, float acc) {
#if __has_builtin(__builtin_amdgcn_fdot2)
  h2 c = __builtin_bit_cast(h2, cw);
  return __builtin_amdgcn_fdot2(c, w, acc, false);
#else
  return fmaf(h_hi(cw), (float)w[1], fmaf(h_lo(cw), (float)w[0], acc));
#endif
}

// ---------------------------------------------------------------------------
// Fused GEMM: atomh[M x 384](f16) = silu(ns @ W1 + b1) @ W2 + b2
// h tile lives only in LDS (As reused after phase 1).
// ---------------------------------------------------------------------------
__global__ __launch_bounds__(256) void gemm_fused(
    const float* __restrict__ A, const float* __restrict__ W1,
    const float* __restrict__ b1, const float* __restrict__ W2,
    const float* __restrict__ b2, ushort* __restrict__ atomh, int M) {
  __shared__ float As[64][FDIM + 4];
  const int row0 = blockIdx.x * 64;
  const int t = threadIdx.x;
  const int tx = t & 15;
  const int ty = t >> 4;
  const int cl = tx * 8;
  const int r0 = ty * 4;

  for (int i = t; i < 64 * 32; i += 256) {
    int r = i >> 5;
    int cc = (i & 31) << 2;
    int gr = row0 + r;
    float4 v = make_float4(0.f, 0.f, 0.f, 0.f);
    if (gr < M) v = *(const float4*)&A[(size_t)gr * FDIM + cc];
    *(float4*)&As[r][cc] = v;
  }
  __syncthreads();

  float acc[4][8];
#pragma unroll
  for (int r = 0; r < 4; ++r)
#pragma unroll
    for (int c = 0; c < 8; ++c) acc[r][c] = 0.f;
#pragma unroll 4
  for (int k = 0; k < FDIM; ++k) {
    const float* wr = W1 + (size_t)k * FDIM + cl;
    float4 wa = *(const float4*)wr;
    float4 wb = *(const float4*)(wr + 4);
    float w[8] = {wa.x, wa.y, wa.z, wa.w, wb.x, wb.y, wb.z, wb.w};
    float a[4];
#pragma unroll
    for (int r = 0; r < 4; ++r) a[r] = As[r0 + r][k];
#pragma unroll
    for (int r = 0; r < 4; ++r)
#pragma unroll
      for (int c = 0; c < 8; ++c) acc[r][c] = fmaf(a[r], w[c], acc[r][c]);
  }
  float hv[4][8];
#pragma unroll
  for (int r = 0; r < 4; ++r)
#pragma unroll
    for (int c = 0; c < 8; ++c) {
      float x = acc[r][c] + b1[cl + c];
      hv[r][c] = x / (1.f + __expf(-x));
    }
  __syncthreads();
#pragma unroll
  for (int r = 0; r < 4; ++r)
#pragma unroll
    for (int c = 0; c < 8; ++c) As[r0 + r][cl + c] = hv[r][c];
  __syncthreads();

#pragma unroll 1
  for (int p = 0; p < 3; ++p) {
    const int c0 = p * 128 + cl;
#pragma unroll
    for (int r = 0; r < 4; ++r)
#pragma unroll
      for (int c = 0; c < 8; ++c) acc[r][c] = 0.f;
#pragma unroll 4
    for (int k = 0; k < FDIM; ++k) {
      const float* wr = W2 + (size_t)k * 384 + c0;
      float4 wa = *(const float4*)wr;
      float4 wb = *(const float4*)(wr + 4);
      float w[8] = {wa.x, wa.y, wa.z, wa.w, wb.x, wb.y, wb.z, wb.w};
      float a[4];
#pragma unroll
      for (int r = 0; r < 4; ++r) a[r] = As[r0 + r][k];
#pragma unroll
      for (int r = 0; r < 4; ++r)
#pragma unroll
        for (int c = 0; c < 8; ++c) acc[r][c] = fmaf(a[r], w[c], acc[r][c]);
    }
#pragma unroll
    for (int r = 0; r < 4; ++r) {
      int gr = row0 + r0 + r;
      if (gr >= M) continue;
      union { ushort s[8]; uint4 q; } pk;
#pragma unroll
      for (int c = 0; c < 8; ++c) pk.s[c] = f2us(acc[r][c] + b2[c0 + c]);
      *(uint4*)&atomh[(size_t)gr * 384 + c0] = pk.q;
    }
  }
}

// ---------------------------------------------------------------------------
// Pack: bundle[i=n*128+j] = 3 uints {(a0,a1),(a2,v0),(v1,v2)} all f16.
// ---------------------------------------------------------------------------
__global__ __launch_bounds__(256) void pack_kernel(
    const ushort* __restrict__ atomh, const float* __restrict__ nvec,
    uint* __restrict__ bundle, int NF) {
  for (int i = blockIdx.x * blockDim.x + threadIdx.x; i < NF;
       i += gridDim.x * blockDim.x) {
    int n = i >> 7, j = i & 127;
    const ushort* ab = atomh + (size_t)n * 384;
    uint a0 = ab[j], a1 = ab[j + 128], a2 = ab[j + 256];
    const float* vb = nvec + (size_t)i * 3;
    uint* o = bundle + (size_t)i * 3;
    o[0] = a0 | (a1 << 16);
    o[1] = a2 | ((uint)f2us(vb[0]) << 16);
    o[2] = (uint)f2us(vb[1]) | ((uint)f2us(vb[2]) << 16);
  }
}

// ---------------------------------------------------------------------------
// CSR build
// ---------------------------------------------------------------------------
__global__ __launch_bounds__(256) void hist_kernel(const float* __restrict__ adj,
                                                   int* __restrict__ counts,
                                                   int E) {
  int e = blockIdx.x * blockDim.x + threadIdx.x;
  if (e < E) atomicAdd(&counts[(int)adj[(size_t)e * 6]], 1);
}

__global__ __launch_bounds__(1024) void scan_kernel(
    const int* __restrict__ counts, int* __restrict__ offs,
    int* __restrict__ cursor, int n) {
  __shared__ int part[1024];
  const int tid = threadIdx.x;
  const int CH = (n + 1023) >> 10;
  const int b = tid * CH;
  const int e = min(b + CH, n);
  int s = 0;
  for (int i = b; i < e; ++i) s += counts[i];
  part[tid] = s;
  __syncthreads();
  for (int off = 1; off < 1024; off <<= 1) {
    int v = (tid >= off) ? part[tid - off] : 0;
    __syncthreads();
    part[tid] += v;
    __syncthreads();
  }
  int run = part[tid] - s;
  if (tid == 0) offs[0] = 0;
  for (int i = b; i < e; ++i) {
    int c = counts[i];
    cursor[i] = run;
    run += c;
    offs[i + 1] = run;
  }
}

// ---------------------------------------------------------------------------
// Edge prep: scatter eid + 64B record:
// w0=src, w1=(rhx,rhy), w2=(rhz,cut), w3..12=(c0..c19), c_n=sin(nx)*invd*cut
// ---------------------------------------------------------------------------
__global__ __launch_bounds__(256) void edge_prep(const float* __restrict__ adj,
                                                 int* __restrict__ cursor,
                                                 int* __restrict__ eids,
                                                 uint* __restrict__ rec, int E) {
  int e = blockIdx.x * blockDim.x + threadIdx.x;
  if (e >= E) return;
  const float* a = adj + (size_t)e * 6;
  int dst = (int)a[0];
  int src = (int)a[1];
  float rx = a[2], ry = a[3], rz = a[4], d = a[5];

  int p = atomicAdd(&cursor[dst], 1);
  eids[p] = e;

  float x = d * (PI_F / CUTOFF_F);
  float sx, cx;
  __sincosf(x, &sx, &cx);
  float invd = 1.f / d;
  float cut = (d < CUTOFF_F) ? 0.5f * (cx + 1.f) : 0.f;
  float sc = invd * cut;

  union { uint w[16]; uint4 q[4]; } R;
  R.w[0] = (uint)src;
  R.w[1] = packh(rx * invd, ry * invd);
  R.w[2] = packh(rz * invd, cut);
  float twoc = 2.f * cx;
  float sprev = 0.f, scur = sx;
  float c[NRBF];
#pragma unroll
  for (int n = 0; n < NRBF; ++n) {
    c[n] = scur * sc;
    float nxt = fmaf(twoc, scur, -sprev);
    sprev = scur;
    scur = nxt;
  }
#pragma unroll
  for (int m = 0; m < 10; ++m) R.w[3 + m] = packh(c[2 * m], c[2 * m + 1]);
  R.w[13] = 0;
  R.w[14] = 0;
  R.w[15] = 0;
  uint4* o = (uint4*)(rec + ((size_t)e << 4));
#pragma unroll
  for (int m = 0; m < 4; ++m) o[m] = R.q[m];
}

// ---------------------------------------------------------------------------
// Persistent per-dst accumulation: 128 threads, grid-stride over dst nodes.
// One dwordx3 gather per edge (packed bundle). Records via scalar loads.
// ---------------------------------------------------------------------------
__global__ __launch_bounds__(128) void accum_kernel(
    const uint* __restrict__ rec, const uint* __restrict__ bundle,
    const float* __restrict__ nvec, const float* __restrict__ Wr,
    const float* __restrict__ br, const float* __restrict__ ns,
    const int* __restrict__ offs, const int* __restrict__ eids,
    float* __restrict__ out_s, float* __restrict__ out_v, int Nn) {
  const int j = threadIdx.x;

  h2 wp0[10], wp1[10], wp2[10];
#pragma unroll
  for (int m = 0; m < 10; ++m) {
    wp0[m] = h2{(_Float16)Wr[(2 * m) * 384 + j], (_Float16)Wr[(2 * m + 1) * 384 + j]};
    wp1[m] = h2{(_Float16)Wr[(2 * m) * 384 + 128 + j], (_Float16)Wr[(2 * m + 1) * 384 + 128 + j]};
    wp2[m] = h2{(_Float16)Wr[(2 * m) * 384 + 256 + j], (_Float16)Wr[(2 * m + 1) * 384 + 256 + j]};
  }
  const float brj0 = br[j], brj1 = br[j + 128], brj2 = br[j + 256];

  __shared__ int sh_e[128], sh_s[128];

#define EID(t) ((t) < 128 ? sh_s[(t)] : eids[beg + (t)])
#define LOADREC(R, t)                                                      \
  {                                                                        \
    int eu = __builtin_amdgcn_readfirstlane(EID(t));                       \
    const uint* p = rec + ((size_t)(uint)eu << 4);                         \
    _Pragma("unroll") for (int w_ = 0; w_ < 13; ++w_) R[w_] = p[w_];       \
  }
#define LOADB(B0, B1, B2, SRC)                                             \
  {                                                                        \
    const uint* p = bundle + ((size_t)(uint)(SRC) * FDIM + j) * 3;         \
    B0 = p[0];                                                             \
    B1 = p[1];                                                             \
    B2 = p[2];                                                             \
  }

  for (int d = blockIdx.x; d < Nn; d += gridDim.x) {
    const int beg = offs[d];
    const int cnt = offs[d + 1] - beg;
    const int m = cnt < 128 ? cnt : 128;
    if (j < m) sh_e[j] = eids[beg + j];
    __syncthreads();
    if (j < m) {  // parallel rank sort (eids unique)
      int v = sh_e[j];
      int r = 0;
      for (int u = 0; u < m; ++u) r += (sh_e[u] < v);
      sh_s[r] = v;
    }
    __syncthreads();

    float acc_s = 0.f, av0 = 0.f, av1 = 0.f, av2 = 0.f;

    uint r_cur[13], r_nxt[13];
    uint b0 = 0, b1 = 0, b2 = 0;
    if (cnt > 0) LOADREC(r_cur, 0);
    if (cnt > 1) LOADREC(r_nxt, 1);
    if (cnt > 0) LOADB(b0, b1, b2, (int)r_cur[0]);

    for (int t = 0; t < cnt; ++t) {
      uint nb0 = 0, nb1 = 0, nb2 = 0;
      if (t + 1 < cnt) LOADB(nb0, nb1, nb2, (int)r_nxt[0]);
      uint r_n2[13];
      if (t + 2 < cnt) LOADREC(r_n2, t + 2);

      float rhx = h_lo(r_cur[1]), rhy = h_hi(r_cur[1]);
      float rhz = h_lo(r_cur[2]), cut = h_hi(r_cur[2]);
      float w0 = cut * brj0, w1 = cut * brj1, w2 = cut * brj2;
#pragma unroll
      for (int q = 0; q < 10; ++q) {
        w0 = dot2(r_cur[3 + q], wp0[q], w0);
        w1 = dot2(r_cur[3 + q], wp1[q], w1);
        w2 = dot2(r_cur[3 + q], wp2[q], w2);
      }
      float s1 = h_lo(b0) * w0;
      float s2 = h_hi(b0) * w1;
      float s3 = h_lo(b1) * w2;
      float pv0 = h_hi(b1), pv1 = h_lo(b2), pv2 = h_hi(b2);
      acc_s += s2;
      av0 = fmaf(pv0, s1, fmaf(s3, rhx, av0));
      av1 = fmaf(pv1, s1, fmaf(s3, rhy, av1));
      av2 = fmaf(pv2, s1, fmaf(s3, rhz, av2));

#pragma unroll
      for (int w_ = 0; w_ < 13; ++w_) {
        r_cur[w_] = r_nxt[w_];
        r_nxt[w_] = r_n2[w_];
      }
      b0 = nb0;
      b1 = nb1;
      b2 = nb2;
    }

    out_s[(size_t)d * FDIM + j] = ns[(size_t)d * FDIM + j] + acc_s;
    float* vo = out_v + (size_t)d * 384 + j * 3;
    const float* vi = nvec + (size_t)d * 384 + j * 3;
    vo[0] = vi[0] + av0;
    vo[1] = vi[1] + av1;
    vo[2] = vi[2] + av2;
  }
#undef EID
#undef LOADREC
#undef LOADB
}

// ---------------------------------------------------------------------------
extern "C" void kernel_launch(void* const* d_in, const int* in_sizes, int n_in,
                              void* d_out, int out_size, void* d_ws,
                              size_t ws_size, hipStream_t stream) {
  const float* node_scalar = (const float*)d_in[0];
  const float* node_vector = (const float*)d_in[1];
  const float* adj = (const float*)d_in[2];
  const float* W1 = (const float*)d_in[3];
  const float* b1 = (const float*)d_in[4];
  const float* W2 = (const float*)d_in[5];
  const float* b2 = (const float*)d_in[6];
  const float* Wr = (const float*)d_in[7];
  const float* br = (const float*)d_in[8];

  const int N = in_sizes[0] / FDIM;
  const int E = in_sizes[2] / 6;

  float* out = (float*)d_out;
  float* out_s = out;
  float* out_v = out + (size_t)N * FDIM;

  // atomh (f16 N x 384 = 19.2MB) lives in d_out — dead until accum's final
  // full overwrite; consumed by pack_kernel before accum runs.
  ushort* atomh = (ushort*)d_out;

  // workspace: bundle (N*128*12B) | counts | offs | cursor | eids
  char* w = (char*)d_ws;
  uint* bundle = (uint*)w;
  size_t off = (size_t)N * FDIM * 12;
  uint* rec = (uint*)(w + off);
  off += (size_t)E * 64;
  int* counts = (int*)(w + off);
  int* offs = counts + N;
  int* cursor = offs + N + 1;
  int* eids = cursor + N;

  hipMemsetAsync(counts, 0, (size_t)N * sizeof(int), stream);
  hist_kernel<<<(E + 255) / 256, 256, 0, stream>>>(adj, counts, E);
  scan_kernel<<<1, 1024, 0, stream>>>(counts, offs, cursor, N);
  edge_prep<<<(E + 255) / 256, 256, 0, stream>>>(adj, cursor, eids, rec, E);

  gemm_fused<<<(N + 63) / 64, 256, 0, stream>>>(node_scalar, W1, b1, W2, b2,
                                                atomh, N);
  pack_kernel<<<2048, 256, 0, stream>>>(atomh, node_vector, bundle, N * FDIM);

  const int agrid = N < 4096 ? N : 4096;
  accum_kernel<<<agrid, 128, 0, stream>>>(rec, bundle, node_vector, Wr, br,
                                          node_scalar, offs, eids, out_s,
                                          out_v, N);
}